// Round 7
// baseline (277.014 us; speedup 1.0000x reference)
//
#include <hip/hip_runtime.h>

typedef __bf16 bf16_t;
typedef bf16_t bf16x8 __attribute__((ext_vector_type(8)));
typedef bf16_t bf16x4 __attribute__((ext_vector_type(4)));
typedef float f32x4 __attribute__((ext_vector_type(4)));

constexpr int BATCH = 4, SEQ = 2048, CH = 1024, NHEAD = 16, HD = 64;
constexpr int BM = 128, BN = 128;

// HW wait + compiler reorder barrier (builtin is IntrNoMem -> unsafe for ordering)
#define LGKM_FENCE() __asm__ __volatile__("s_waitcnt lgkmcnt(0)" ::: "memory")
#define VM_FENCE() __asm__ __volatile__("s_waitcnt vmcnt(0)" ::: "memory")

__device__ __forceinline__ void g2lds16(const bf16_t* g, bf16_t* l) {
  __builtin_amdgcn_global_load_lds((__attribute__((address_space(1))) void*)(g),
                                   (__attribute__((address_space(3))) void*)(l),
                                   16, 0, 0);
}

__device__ __forceinline__ f32x4 mfma16(bf16x8 a, bf16x8 b, f32x4 c) {
  return __builtin_amdgcn_mfma_f32_16x16x32_bf16(a, b, c, 0, 0, 0);
}

// ---------------- fused fp32 -> bf16 conversion (x, w_attn, w_proj) ----------------
__global__ __launch_bounds__(256) void cvt3_kernel(const float4* __restrict__ x,
                                                   ushort4* __restrict__ dx,
                                                   const float4* __restrict__ wa,
                                                   ushort4* __restrict__ dwa,
                                                   const float4* __restrict__ wp,
                                                   ushort4* __restrict__ dwp) {
  int bid = blockIdx.x;
  const float4* s;
  ushort4* d;
  int i;
  if (bid < 8192) {
    s = x; d = dx; i = bid * 256 + threadIdx.x;
  } else if (bid < 11264) {
    s = wa; d = dwa; i = (bid - 8192) * 256 + threadIdx.x;
  } else {
    s = wp; d = dwp; i = (bid - 11264) * 256 + threadIdx.x;
  }
  float4 f = s[i];
  ushort4 o;
  o.x = __builtin_bit_cast(unsigned short, (bf16_t)f.x);
  o.y = __builtin_bit_cast(unsigned short, (bf16_t)f.y);
  o.z = __builtin_bit_cast(unsigned short, (bf16_t)f.z);
  o.w = __builtin_bit_cast(unsigned short, (bf16_t)f.w);
  d[i] = o;
}

// ------- stage-ahead double-buffered GEMM mainloop (C = A * W^T), BK=32 -------
// T3/T4-minimum: iter t issues the t+1 stage into buf^1 FIRST, then waits
// vmcnt(4) (previous stage only; the 4 new loads fly through the compute phase),
// barrier, ds_read+MFMA, barrier. LDS = 2*(MR+NR)*32*2B (qkv 32KB: keeps 4
// CTAs/CU). Swizzle: 16B slots XOR'd by (row>>1)&3 -> fragment reads hit 8 bank
// starts x 2 lanes (conflict-free, same profile as the verified BK=64 layout);
// swizzle applied on the GLOBAL source col (rule 21), LDS dest stays linear.
template <int MFRAG, int NFRAG>
__device__ __forceinline__ void gemm_db(const bf16_t* __restrict__ A,
                                        const bf16_t* __restrict__ W,
                                        int Kdim, int m0, int n0,
                                        bf16_t* lds, f32x4 acc[MFRAG][NFRAG]) {
  constexpr int MR = MFRAG * 32, NR = NFRAG * 32;  // block tile dims
  constexpr int AP = MR / 64, BP = NR / 64;        // 64-row staging passes
  constexpr int ASZ = MR * 32, BSZ = NR * 32, BUF = ASZ + BSZ;
  const int tid = threadIdx.x, lane = tid & 63, w = tid >> 6;
  const int quad = lane >> 4, l16 = lane & 15;
  const int wm = (w >> 1) * (MFRAG * 16), wn = (w & 1) * (NFRAG * 16);
  const int srow = tid >> 2;                            // 0..63 within a pass
  const int scol = (((tid & 3) ^ ((tid >> 3) & 3)) << 3);  // pre-swizzled src col
  const int dbase = srow * 32 + ((tid & 3) << 3);       // linear LDS dest (lane*8)
  const int key = (l16 >> 1) & 3;                       // read swizzle key
  const bf16_t* gA[AP];
  const bf16_t* gB[BP];
#pragma unroll
  for (int p = 0; p < AP; p++)
    gA[p] = A + (size_t)(m0 + p * 64 + srow) * Kdim + scol;
#pragma unroll
  for (int p = 0; p < BP; p++)
    gB[p] = W + (size_t)(n0 + p * 64 + srow) * Kdim + scol;

  auto stage = [&](int b, int k0) {
#pragma unroll
    for (int p = 0; p < AP; p++)
      g2lds16(gA[p] + k0, lds + b * BUF + p * 2048 + dbase);
#pragma unroll
    for (int p = 0; p < BP; p++)
      g2lds16(gB[p] + k0, lds + b * BUF + ASZ + p * 2048 + dbase);
  };

  stage(0, 0);
  const int NIT = Kdim >> 5;
  for (int t = 0; t < NIT; t++) {
    const int b = t & 1;
    if (t + 1 < NIT) stage(b ^ 1, (t + 1) << 5);
    __builtin_amdgcn_sched_barrier(0);  // pin: issue-before-wait
    if (t + 1 < NIT) {
      if constexpr (AP + BP == 4)
        asm volatile("s_waitcnt vmcnt(4)" ::: "memory");
      else
        asm volatile("s_waitcnt vmcnt(3)" ::: "memory");
    } else {
      VM_FENCE();
    }
    __syncthreads();  // publish buf b (all waves' prev-stage writes landed)
    const bf16_t* Ab = lds + b * BUF;
    const bf16_t* Bb = Ab + ASZ;
    bf16x8 av[MFRAG], bv[NFRAG];
#pragma unroll
    for (int i = 0; i < MFRAG; i++)
      av[i] = *(const bf16x8*)&Ab[(wm + i * 16 + l16) * 32 + ((quad ^ key) << 3)];
#pragma unroll
    for (int i = 0; i < NFRAG; i++)
      bv[i] = *(const bf16x8*)&Bb[(wn + i * 16 + l16) * 32 + ((quad ^ key) << 3)];
#pragma unroll
    for (int mi = 0; mi < MFRAG; mi++)
#pragma unroll
      for (int ni = 0; ni < NFRAG; ni++)
        acc[mi][ni] = mfma16(av[mi], bv[ni], acc[mi][ni]);
    __syncthreads();  // all reads of buf b done before t+1 overwrites it
  }
}

// ---------------- QKV GEMM + bias + RoPE + scatter ----------------
constexpr float SCL = 0.125f * 1.44269504089f;  // 1/sqrt(64) * log2(e), folded into Q

__global__ __launch_bounds__(256) void qkv_rope_kernel(
    const bf16_t* __restrict__ X, const bf16_t* __restrict__ Wa,
    const float* __restrict__ ba, const float* __restrict__ cosT,
    const float* __restrict__ sinT, bf16_t* __restrict__ Q,
    bf16_t* __restrict__ Ko, bf16_t* __restrict__ VT) {
  constexpr int TSTRIDE = 68;
  __shared__ __align__(16) char smem[4 * 64 * TSTRIDE * 2];  // 34816 B >= 32KB dbuf

  f32x4 acc[4][4];
#pragma unroll
  for (int i = 0; i < 4; i++)
#pragma unroll
    for (int j = 0; j < 4; j++) acc[i][j] = (f32x4){0.f, 0.f, 0.f, 0.f};

  // T1 XCD swizzle: 1536 blocks, 192 per XCD (8 consecutive m-rows x all 24 n-tiles)
  const int id = blockIdx.x;
  const int sid = ((id & 7) * 192) + (id >> 3);
  const int n0 = (sid % 24) * BN;
  const int m0 = (sid / 24) * BM;
  gemm_db<4, 4>(X, Wa, CH, m0, n0, (bf16_t*)smem, acc);

  const int tid = threadIdx.x, lane = tid & 63, w = tid >> 6;
  const int quad = lane >> 4, l16 = lane & 15;
  const int wm = (w >> 1) << 6, wn = (w & 1) << 6;
  const int nbase = n0 + wn;
  const int part = nbase >> 10;
  const int h = (nbase & 1023) >> 6;
  const int mbase = m0 + wm;
  const int bb = mbase >> 11;
  const size_t headbase = ((size_t)(bb * NHEAD + h)) * SEQ * HD;

  if (part < 2) {
    bf16_t* O = (part == 0) ? Q : Ko;
    const float post = (part == 0) ? SCL : 1.0f;  // fold softmax scale into Q
#pragma unroll
    for (int mi = 0; mi < 4; mi++)
#pragma unroll
      for (int r = 0; r < 4; r++) {
        int m = mbase + mi * 16 + quad * 4 + r;
        int t = m & (SEQ - 1);
        const float* cr = cosT + t * HD;
        const float* sr = sinT + t * HD;
        size_t rowo = headbase + (size_t)t * HD;
#pragma unroll
        for (int ni = 0; ni < 2; ni++) {
          int d0 = ni * 16 + l16, d1 = d0 + 32;
          float v0 = acc[mi][ni][r] + ba[nbase + d0];
          float v1 = acc[mi][ni + 2][r] + ba[nbase + d1];
          float r0 = (v0 * cr[d0] - v1 * sr[d0]) * post;
          float r1 = (v1 * cr[d1] + v0 * sr[d1]) * post;
          O[rowo + d0] = (bf16_t)r0;
          O[rowo + d1] = (bf16_t)r1;
        }
      }
  } else {
    bf16_t* tb = (bf16_t*)smem + w * 64 * TSTRIDE;
    int t0 = mbase & (SEQ - 1);
#pragma unroll
    for (int mi = 0; mi < 4; mi++)
#pragma unroll
      for (int ni = 0; ni < 4; ni++) {
        int d = ni * 16 + l16;
        float bias = ba[nbase + d];
#pragma unroll
        for (int r = 0; r < 4; r++) {
          float v = acc[mi][ni][r] + bias;
          tb[d * TSTRIDE + mi * 16 + quad * 4 + r] = (bf16_t)v;
        }
      }
    LGKM_FENCE();  // same-wave LDS RAW
    int half = lane >> 5, l5 = lane & 31;
    size_t vbase = ((size_t)(bb * NHEAD + h)) * HD * SEQ;
#pragma unroll
    for (int it = 0; it < 32; it++) {
      int d = it * 2 + half;
      unsigned int val = *(const unsigned int*)&tb[d * TSTRIDE + l5 * 2];
      *(unsigned int*)&VT[vbase + (size_t)d * SEQ + t0 + l5 * 2] = val;
    }
  }
}

// ---------------- flash attention v11: v8 geometry + MFMA row-sum ----------------
// v8 structure (1024 CTAs, paired 64-row jobs, 33 chunks, 40KB LDS) with the
// softmax row-sum on the MFMA pipe: mfma(ones, P) accumulates sum_k P[k][q]
// (masked slots hold P=0, exact). Removes the per-chunk VALU add chain.
__device__ __forceinline__ void sm_update(f32x4 (&s)[4], bf16_t* Prow, int quad,
                                          int swz, bool domask, int lim) {
  if (domask) {
#pragma unroll
    for (int ni = 0; ni < 4; ni++)
#pragma unroll
      for (int r = 0; r < 4; r++)
        if (ni * 16 + r > lim) s[ni][r] = -1e30f;
  }
#pragma unroll
  for (int ni = 0; ni < 4; ni++) {
    float p0 = __builtin_exp2f(s[ni][0]);
    float p1 = __builtin_exp2f(s[ni][1]);
    float p2 = __builtin_exp2f(s[ni][2]);
    float p3 = __builtin_exp2f(s[ni][3]);
    bf16x4 pk = {(bf16_t)p0, (bf16_t)p1, (bf16_t)p2, (bf16_t)p3};
    // slot = ni*4+quad (8B units), phys = slot ^ (swz<<1) -> 4 elem offset
    *(bf16x4*)&Prow[(((ni << 2) | quad) ^ (swz << 1)) << 2] = pk;
  }
}

__global__ __launch_bounds__(256) void flash_kernel(const bf16_t* __restrict__ Q,
                                                    const bf16_t* __restrict__ Kg,
                                                    const bf16_t* __restrict__ VT,
                                                    bf16_t* __restrict__ att) {
  __shared__ __align__(16) bf16_t Ks[2][64 * 64];
  __shared__ __align__(16) bf16_t Vs[2][64 * 64];
  __shared__ __align__(16) bf16_t Pt[4][16 * 64];  // one shared tile per wave
  const int tid = threadIdx.x, w = tid >> 6, lane = tid & 63;
  const int quad = lane >> 4, l16 = lane & 15;
  const int p = (int)blockIdx.x >> 6;
  const int bh = (int)blockIdx.x & 63;
  const bf16_t* Qp = Q + (size_t)bh * SEQ * HD;
  const bf16_t* Kb = Kg + (size_t)bh * SEQ * HD;
  const bf16_t* Vb = VT + (size_t)bh * HD * SEQ;
  const int grow = lane >> 3;
  const int gj8 = ((lane & 7) ^ grow) * 8;
  const int i0 = w * 2;
  const int sw = l16 & 7;
  const int swz = l16 >> 1;                      // P-tile row swizzle key
  const int bloc = bh >> 4, hh = bh & 15;
  bf16_t* Pw = &Pt[w][l16 * 64];                 // row base (q = l16)
  const int rs0 = (quad ^ swz) << 3;             // read frag g=0 elem offset
  const int rs1 = ((4 + quad) ^ swz) << 3;       // read frag g=1 elem offset

  const bf16x8 ones = {(bf16_t)1.f, (bf16_t)1.f, (bf16_t)1.f, (bf16_t)1.f,
                       (bf16_t)1.f, (bf16_t)1.f, (bf16_t)1.f, (bf16_t)1.f};

  auto stage = [&](int kcs, int b) {
#pragma unroll
    for (int ii = 0; ii < 2; ii++) {
      int i = i0 + ii;
      g2lds16(Kb + (size_t)(kcs + i * 8 + grow) * HD + gj8, &Ks[b][(i * 64 + lane) * 8]);
      g2lds16(Vb + (size_t)(i * 8 + grow) * SEQ + kcs + gj8, &Vs[b][(i * 64 + lane) * 8]);
    }
  };

  for (int sp = 0; sp < 2; ++sp) {
    const int j = sp ? p : 31 - p;      // paired jobs: (32-p) + (p+1) = 33 chunks
    const int m = j * 64 + w * 16;      // this wave's 16 q-rows
    const int nch = j + 1;
    bf16x8 aq0 = *(const bf16x8*)&Qp[(size_t)(m + l16) * HD + quad * 8];
    bf16x8 aq1 = *(const bf16x8*)&Qp[(size_t)(m + l16) * HD + 32 + quad * 8];
    f32x4 y[4];
    f32x4 sum_acc = (f32x4){0.f, 0.f, 0.f, 0.f};
#pragma unroll
    for (int ni = 0; ni < 4; ni++) y[ni] = (f32x4){0.f, 0.f, 0.f, 0.f};

    stage(0, 0);
    VM_FENCE();
    __syncthreads();

    for (int c = 0; c < nch; ++c) {
      const int kc = c * 64, buf = c & 1;
      if (c + 1 < nch) stage(kc + 64, buf ^ 1);
      f32x4 s[4];
#pragma unroll
      for (int ni = 0; ni < 4; ni++) {
        bf16x8 k0 = *(const bf16x8*)&Ks[buf][((ni * 16 + l16) * 8 + (quad ^ sw)) * 8];
        bf16x8 k1 = *(const bf16x8*)&Ks[buf][((ni * 16 + l16) * 8 + ((4 + quad) ^ sw)) * 8];
        f32x4 z = (f32x4){0.f, 0.f, 0.f, 0.f};
        s[ni] = mfma16(k1, aq1, mfma16(k0, aq0, z));
      }
      sm_update(s, Pw, quad, swz, c == nch - 1, m + l16 - kc - quad * 4);
      LGKM_FENCE();
      bf16x8 p0 = *(const bf16x8*)&Pw[rs0];
      bf16x8 p1 = *(const bf16x8*)&Pw[rs1];
      // row-sum on the MFMA pipe: sum_acc[.][q=l16] += sum_k P[k][q]
      sum_acc = mfma16(ones, p1, mfma16(ones, p0, sum_acc));
#pragma unroll
      for (int ni = 0; ni < 4; ni++) {
        bf16x8 v0 = *(const bf16x8*)&Vs[buf][((ni * 16 + l16) * 8 + (quad ^ sw)) * 8];
        bf16x8 v1 = *(const bf16x8*)&Vs[buf][((ni * 16 + l16) * 8 + ((4 + quad) ^ sw)) * 8];
        y[ni] = mfma16(v1, p1, mfma16(v0, p0, y[ni]));
      }
      VM_FENCE();  // prefetch DMA drained before publishing buffers
      __syncthreads();
    }

    // epilogue: y^T[d][q], d = ni*16+quad*4+r, q = l16; sum_acc holds full row-sum
    float inv = 1.f / sum_acc[0];
    size_t rb = ((size_t)bloc * SEQ + m + l16) * CH + hh * HD + quad * 4;
#pragma unroll
    for (int ni = 0; ni < 4; ni++) {
      bf16x4 o = {(bf16_t)(y[ni][0] * inv), (bf16_t)(y[ni][1] * inv),
                  (bf16_t)(y[ni][2] * inv), (bf16_t)(y[ni][3] * inv)};
      *(bf16x4*)&att[rb + ni * 16] = o;
    }
  }
}

// ---------------- output projection GEMM: 64x128 tiles, stage-ahead dbuf --------
__global__ __launch_bounds__(256) void proj_kernel(const bf16_t* __restrict__ A,
                                                   const bf16_t* __restrict__ Wp,
                                                   const float* __restrict__ bp,
                                                   float* __restrict__ out) {
  __shared__ __align__(16) bf16_t lds[2 * (64 * 32 + 128 * 32)];  // 24 KB
  f32x4 acc[2][4];
#pragma unroll
  for (int i = 0; i < 2; i++)
#pragma unroll
    for (int j = 0; j < 4; j++) acc[i][j] = (f32x4){0.f, 0.f, 0.f, 0.f};

  // T1 XCD swizzle: 1024 blocks, 128 per XCD; n fastest -> full W cycles in L2.
  const int id = blockIdx.x;
  const int sid = ((id & 7) * 128) + (id >> 3);
  const int n0 = (sid % 8) * 128;
  const int m0 = (sid / 8) * 64;
  gemm_db<2, 4>(A, Wp, CH, m0, n0, lds, acc);

  const int tid = threadIdx.x, lane = tid & 63, w = tid >> 6;
  const int quad = lane >> 4, l16 = lane & 15;
  const int wm = (w >> 1) << 5, wn = (w & 1) << 6;
  const int nbase = n0 + wn, mbase = m0 + wm;
#pragma unroll
  for (int mi = 0; mi < 2; mi++)
#pragma unroll
    for (int r = 0; r < 4; r++) {
      int m = mbase + mi * 16 + quad * 4 + r;
#pragma unroll
      for (int ni = 0; ni < 4; ni++) {
        int n = nbase + ni * 16 + l16;
        out[(size_t)m * CH + n] = acc[mi][ni][r] + bp[n];
      }
    }
}

extern "C" void kernel_launch(void* const* d_in, const int* in_sizes, int n_in,
                              void* d_out, int out_size, void* d_ws, size_t ws_size,
                              hipStream_t stream) {
  const float* x      = (const float*)d_in[0];
  const float* w_attn = (const float*)d_in[1];
  const float* b_attn = (const float*)d_in[2];
  const float* w_proj = (const float*)d_in[3];
  const float* b_proj = (const float*)d_in[4];
  const float* cosT   = (const float*)d_in[5];
  const float* sinT   = (const float*)d_in[6];
  float* out = (float*)d_out;

  bf16_t* xbf  = (bf16_t*)d_ws;
  bf16_t* wabf = xbf + (size_t)8192 * 1024;
  bf16_t* wpbf = wabf + (size_t)3072 * 1024;
  bf16_t* Qb   = wpbf + (size_t)1024 * 1024;
  bf16_t* Kb   = Qb + (size_t)8388608;
  bf16_t* VTb  = Kb + (size_t)8388608;
  bf16_t* attb = VTb + (size_t)8388608;

  cvt3_kernel<<<12288, 256, 0, stream>>>((const float4*)x, (ushort4*)xbf,
                                         (const float4*)w_attn, (ushort4*)wabf,
                                         (const float4*)w_proj, (ushort4*)wpbf);
  qkv_rope_kernel<<<dim3(1536), 256, 0, stream>>>(xbf, wabf, b_attn, cosT, sinT,
                                                  Qb, Kb, VTb);
  flash_kernel<<<dim3(1024), 256, 0, stream>>>(Qb, Kb, VTb, attb);
  proj_kernel<<<dim3(1024), 256, 0, stream>>>(attb, wpbf, b_proj, out);
}

// Round 8
// 255.636 us; speedup vs baseline: 1.0836x; 1.0836x over previous
//
#include <hip/hip_runtime.h>

typedef __bf16 bf16_t;
typedef bf16_t bf16x8 __attribute__((ext_vector_type(8)));
typedef bf16_t bf16x4 __attribute__((ext_vector_type(4)));
typedef float f32x4 __attribute__((ext_vector_type(4)));

constexpr int BATCH = 4, SEQ = 2048, CH = 1024, NHEAD = 16, HD = 64;
constexpr int BM = 128, BN = 128, BKK = 64;  // BK=64: halves barrier-drain count

// HW wait + compiler reorder barrier (builtin is IntrNoMem -> unsafe for ordering)
#define LGKM_FENCE() __asm__ __volatile__("s_waitcnt lgkmcnt(0)" ::: "memory")
#define VM_FENCE() __asm__ __volatile__("s_waitcnt vmcnt(0)" ::: "memory")

__device__ __forceinline__ void g2lds16(const bf16_t* g, bf16_t* l) {
  __builtin_amdgcn_global_load_lds((__attribute__((address_space(1))) void*)(g),
                                   (__attribute__((address_space(3))) void*)(l),
                                   16, 0, 0);
}

__device__ __forceinline__ f32x4 mfma16(bf16x8 a, bf16x8 b, f32x4 c) {
  return __builtin_amdgcn_mfma_f32_16x16x32_bf16(a, b, c, 0, 0, 0);
}

// ---------------- fused fp32 -> bf16 conversion (x, w_attn, w_proj) ----------------
__global__ __launch_bounds__(256) void cvt3_kernel(const float4* __restrict__ x,
                                                   ushort4* __restrict__ dx,
                                                   const float4* __restrict__ wa,
                                                   ushort4* __restrict__ dwa,
                                                   const float4* __restrict__ wp,
                                                   ushort4* __restrict__ dwp) {
  int bid = blockIdx.x;
  const float4* s;
  ushort4* d;
  int i;
  if (bid < 8192) {
    s = x; d = dx; i = bid * 256 + threadIdx.x;
  } else if (bid < 11264) {
    s = wa; d = dwa; i = (bid - 8192) * 256 + threadIdx.x;
  } else {
    s = wp; d = dwp; i = (bid - 11264) * 256 + threadIdx.x;
  }
  float4 f = s[i];
  ushort4 o;
  o.x = __builtin_bit_cast(unsigned short, (bf16_t)f.x);
  o.y = __builtin_bit_cast(unsigned short, (bf16_t)f.y);
  o.z = __builtin_bit_cast(unsigned short, (bf16_t)f.z);
  o.w = __builtin_bit_cast(unsigned short, (bf16_t)f.w);
  d[i] = o;
}

// ---------------- shared GEMM mainloop (C = A * W^T), BK=64 + T2 swizzle ----------
// LDS layout: [row][64] with 16B slots XOR-swizzled by (row&7). global_load_lds
// writes linearly, so the swizzle is applied on the GLOBAL source column (rule 21).
// NOTE (R7 lesson): stage-ahead dbuf at BK=32 regressed 83->96us (2x barriers);
// this 2-barrier BK=64 form is the verified optimum for this structure.
__device__ __forceinline__ void gemm_mainloop(const bf16_t* __restrict__ A,
                                              const bf16_t* __restrict__ W, int Kdim,
                                              int m0, int n0,
                                              bf16_t* As, bf16_t* Bs,
                                              f32x4 acc[4][4]) {
  const int tid = threadIdx.x;
  const int lane = tid & 63;
  const int w = tid >> 6;
  const int quad = lane >> 4, l16 = lane & 15;
  const int wm = (w >> 1) << 6, wn = (w & 1) << 6;
  const int srow = tid >> 3;                          // 0..31 (row within 32-row pass)
  const int scol = ((tid & 7) ^ (srow & 7)) << 3;     // pre-swizzled source col (elems)
  const int dcol = (tid & 7) << 3;                    // linear LDS dest col
  const int key = l16 & 7;                            // read swizzle key = row & 7
  const bf16_t* ga[4];
  const bf16_t* gb[4];
  bf16_t *la[4], *lb[4];
#pragma unroll
  for (int p = 0; p < 4; p++) {
    int row = p * 32 + srow;
    ga[p] = A + (size_t)(m0 + row) * Kdim + scol;
    gb[p] = W + (size_t)(n0 + row) * Kdim + scol;
    la[p] = As + row * BKK + dcol;
    lb[p] = Bs + row * BKK + dcol;
  }
  for (int k0 = 0; k0 < Kdim; k0 += BKK) {
#pragma unroll
    for (int p = 0; p < 4; p++) g2lds16(ga[p] + k0, la[p]);
#pragma unroll
    for (int p = 0; p < 4; p++) g2lds16(gb[p] + k0, lb[p]);
    VM_FENCE();  // DMA drain before publish
    __syncthreads();
#pragma unroll
    for (int ki = 0; ki < 2; ki++) {
      bf16x8 av[4], bv[4];
#pragma unroll
      for (int i = 0; i < 4; i++)
        av[i] = *(const bf16x8*)&As[(wm + i * 16 + l16) * BKK +
                                    ((((ki << 2) | quad) ^ key) << 3)];
#pragma unroll
      for (int i = 0; i < 4; i++)
        bv[i] = *(const bf16x8*)&Bs[(wn + i * 16 + l16) * BKK +
                                    ((((ki << 2) | quad) ^ key) << 3)];
#pragma unroll
      for (int mi = 0; mi < 4; mi++)
#pragma unroll
        for (int ni = 0; ni < 4; ni++)
          acc[mi][ni] = mfma16(av[mi], bv[ni], acc[mi][ni]);
    }
    __syncthreads();
  }
}

// ---------------- QKV GEMM + bias + RoPE + scatter ----------------
constexpr float SCL = 0.125f * 1.44269504089f;  // 1/sqrt(64) * log2(e), folded into Q

__global__ __launch_bounds__(256) void qkv_rope_kernel(
    const bf16_t* __restrict__ X, const bf16_t* __restrict__ Wa,
    const float* __restrict__ ba, const float* __restrict__ cosT,
    const float* __restrict__ sinT, bf16_t* __restrict__ Q,
    bf16_t* __restrict__ Ko, bf16_t* __restrict__ VT) {
  constexpr int TSTRIDE = 68;
  __shared__ __align__(16) char smem[4 * 64 * TSTRIDE * 2];  // 34816 B >= 32 KB As+Bs
  bf16_t* As = (bf16_t*)smem;
  bf16_t* Bs = As + BM * BKK;

  f32x4 acc[4][4];
#pragma unroll
  for (int i = 0; i < 4; i++)
#pragma unroll
    for (int j = 0; j < 4; j++) acc[i][j] = (f32x4){0.f, 0.f, 0.f, 0.f};

  // T1 XCD swizzle: 1536 blocks, 192 per XCD (8 consecutive m-rows x all 24 n-tiles)
  const int id = blockIdx.x;
  const int sid = ((id & 7) * 192) + (id >> 3);
  const int n0 = (sid % 24) * BN;
  const int m0 = (sid / 24) * BM;
  gemm_mainloop(X, Wa, CH, m0, n0, As, Bs, acc);

  const int tid = threadIdx.x, lane = tid & 63, w = tid >> 6;
  const int quad = lane >> 4, l16 = lane & 15;
  const int wm = (w >> 1) << 6, wn = (w & 1) << 6;
  const int nbase = n0 + wn;
  const int part = nbase >> 10;
  const int h = (nbase & 1023) >> 6;
  const int mbase = m0 + wm;
  const int bb = mbase >> 11;
  const size_t headbase = ((size_t)(bb * NHEAD + h)) * SEQ * HD;

  if (part < 2) {
    bf16_t* O = (part == 0) ? Q : Ko;
    const float post = (part == 0) ? SCL : 1.0f;  // fold softmax scale into Q
#pragma unroll
    for (int mi = 0; mi < 4; mi++)
#pragma unroll
      for (int r = 0; r < 4; r++) {
        int m = mbase + mi * 16 + quad * 4 + r;
        int t = m & (SEQ - 1);
        const float* cr = cosT + t * HD;
        const float* sr = sinT + t * HD;
        size_t rowo = headbase + (size_t)t * HD;
#pragma unroll
        for (int ni = 0; ni < 2; ni++) {
          int d0 = ni * 16 + l16, d1 = d0 + 32;
          float v0 = acc[mi][ni][r] + ba[nbase + d0];
          float v1 = acc[mi][ni + 2][r] + ba[nbase + d1];
          float r0 = (v0 * cr[d0] - v1 * sr[d0]) * post;
          float r1 = (v1 * cr[d1] + v0 * sr[d1]) * post;
          O[rowo + d0] = (bf16_t)r0;
          O[rowo + d1] = (bf16_t)r1;
        }
      }
  } else {
    bf16_t* tb = (bf16_t*)smem + w * 64 * TSTRIDE;
    int t0 = mbase & (SEQ - 1);
#pragma unroll
    for (int mi = 0; mi < 4; mi++)
#pragma unroll
      for (int ni = 0; ni < 4; ni++) {
        int d = ni * 16 + l16;
        float bias = ba[nbase + d];
#pragma unroll
        for (int r = 0; r < 4; r++) {
          float v = acc[mi][ni][r] + bias;
          tb[d * TSTRIDE + mi * 16 + quad * 4 + r] = (bf16_t)v;
        }
      }
    LGKM_FENCE();  // same-wave LDS RAW
    int half = lane >> 5, l5 = lane & 31;
    size_t vbase = ((size_t)(bb * NHEAD + h)) * HD * SEQ;
#pragma unroll
    for (int it = 0; it < 32; it++) {
      int d = it * 2 + half;
      unsigned int val = *(const unsigned int*)&tb[d * TSTRIDE + l5 * 2];
      *(unsigned int*)&VT[vbase + (size_t)d * SEQ + t0 + l5 * 2] = val;
    }
  }
}

// ---------------- flash attention v12: 8-wave CTAs, shared staging ----------------
// v8 schedule per wave, but 512-thread CTAs own 128-row jobs: the staged 64x64
// K/V chunk is shared by 8 waves (per-wave staging DMA+VALU halved; chunk
// stagings 33792 -> 17408) at UNCHANGED occupancy (512 CTAs = 2/CU x 8 waves =
// 16 waves/CU, v8's level; v9's regression was the occupancy loss, not sharing).
// Jobs jb=0..15 paired (15-p, p) -> uniform 34 chunks/CTA. Waves fully above
// the diagonal skip compute (barriers kept). MFMA row-sum as v11.
__device__ __forceinline__ void sm_update(f32x4 (&s)[4], bf16_t* Prow, int quad,
                                          int swz, bool domask, int lim) {
  if (domask) {
#pragma unroll
    for (int ni = 0; ni < 4; ni++)
#pragma unroll
      for (int r = 0; r < 4; r++)
        if (ni * 16 + r > lim) s[ni][r] = -1e30f;
  }
#pragma unroll
  for (int ni = 0; ni < 4; ni++) {
    float p0 = __builtin_exp2f(s[ni][0]);
    float p1 = __builtin_exp2f(s[ni][1]);
    float p2 = __builtin_exp2f(s[ni][2]);
    float p3 = __builtin_exp2f(s[ni][3]);
    bf16x4 pk = {(bf16_t)p0, (bf16_t)p1, (bf16_t)p2, (bf16_t)p3};
    // slot = ni*4+quad (8B units), phys = slot ^ (swz<<1) -> 4 elem offset
    *(bf16x4*)&Prow[(((ni << 2) | quad) ^ (swz << 1)) << 2] = pk;
  }
}

__global__ __launch_bounds__(512, 4) void flash_kernel(const bf16_t* __restrict__ Q,
                                                       const bf16_t* __restrict__ Kg,
                                                       const bf16_t* __restrict__ VT,
                                                       bf16_t* __restrict__ att) {
  __shared__ __align__(16) bf16_t Ks[2][64 * 64];
  __shared__ __align__(16) bf16_t Vs[2][64 * 64];
  __shared__ __align__(16) bf16_t Pt[8][16 * 64];  // one tile per wave (16 KB)
  const int tid = threadIdx.x, w = tid >> 6, lane = tid & 63;
  const int quad = lane >> 4, l16 = lane & 15;
  const int p = (int)blockIdx.x >> 6;            // 0..7 (job-pair index)
  const int bh = (int)blockIdx.x & 63;
  const bf16_t* Qp = Q + (size_t)bh * SEQ * HD;
  const bf16_t* Kb = Kg + (size_t)bh * SEQ * HD;
  const bf16_t* Vb = VT + (size_t)bh * HD * SEQ;
  const int grow = lane >> 3;
  const int gj8 = ((lane & 7) ^ grow) * 8;
  const int sw = l16 & 7;
  const int swz = l16 >> 1;                      // P-tile row swizzle key
  const int bloc = bh >> 4, hh = bh & 15;
  bf16_t* Pw = &Pt[w][l16 * 64];                 // row base (q = l16)
  const int rs0 = (quad ^ swz) << 3;             // read frag g=0 elem offset
  const int rs1 = ((4 + quad) ^ swz) << 3;       // read frag g=1 elem offset

  const bf16x8 ones = {(bf16_t)1.f, (bf16_t)1.f, (bf16_t)1.f, (bf16_t)1.f,
                       (bf16_t)1.f, (bf16_t)1.f, (bf16_t)1.f, (bf16_t)1.f};

  // one K + one V g2lds per wave per chunk (8 waves cover the 64x64 chunk)
  auto stage = [&](int kcs, int b) {
    g2lds16(Kb + (size_t)(kcs + w * 8 + grow) * HD + gj8, &Ks[b][(w * 64 + lane) * 8]);
    g2lds16(Vb + (size_t)(w * 8 + grow) * SEQ + kcs + gj8, &Vs[b][(w * 64 + lane) * 8]);
  };

  for (int sp = 0; sp < 2; ++sp) {
    const int jb = sp ? p : 15 - p;     // paired jobs: (32-2p) + (2p+2) = 34 chunks
    const int m = jb * 128 + w * 16;    // this wave's 16 q-rows
    const int nch = 2 * jb + 2;
    bf16x8 aq0 = *(const bf16x8*)&Qp[(size_t)(m + l16) * HD + quad * 8];
    bf16x8 aq1 = *(const bf16x8*)&Qp[(size_t)(m + l16) * HD + 32 + quad * 8];
    f32x4 y[4];
    f32x4 sum_acc = (f32x4){0.f, 0.f, 0.f, 0.f};
#pragma unroll
    for (int ni = 0; ni < 4; ni++) y[ni] = (f32x4){0.f, 0.f, 0.f, 0.f};

    stage(0, 0);
    VM_FENCE();
    __syncthreads();

    for (int c = 0; c < nch; ++c) {
      const int kc = c * 64, buf = c & 1;
      if (c + 1 < nch) stage(kc + 64, buf ^ 1);
      const bool act = (kc <= m + 15);  // chunk intersects this wave's rows
      if (act) {
        f32x4 s[4];
#pragma unroll
        for (int ni = 0; ni < 4; ni++) {
          bf16x8 k0 = *(const bf16x8*)&Ks[buf][((ni * 16 + l16) * 8 + (quad ^ sw)) * 8];
          bf16x8 k1 = *(const bf16x8*)&Ks[buf][((ni * 16 + l16) * 8 + ((4 + quad) ^ sw)) * 8];
          f32x4 z = (f32x4){0.f, 0.f, 0.f, 0.f};
          s[ni] = mfma16(k1, aq1, mfma16(k0, aq0, z));
        }
        sm_update(s, Pw, quad, swz, kc + 63 > m, m + l16 - kc - quad * 4);
        LGKM_FENCE();
        bf16x8 p0 = *(const bf16x8*)&Pw[rs0];
        bf16x8 p1 = *(const bf16x8*)&Pw[rs1];
        // row-sum on the MFMA pipe: sum_acc[.][q=l16] += sum_k P[k][q]
        sum_acc = mfma16(ones, p1, mfma16(ones, p0, sum_acc));
#pragma unroll
        for (int ni = 0; ni < 4; ni++) {
          bf16x8 v0 = *(const bf16x8*)&Vs[buf][((ni * 16 + l16) * 8 + (quad ^ sw)) * 8];
          bf16x8 v1 = *(const bf16x8*)&Vs[buf][((ni * 16 + l16) * 8 + ((4 + quad) ^ sw)) * 8];
          y[ni] = mfma16(v1, p1, mfma16(v0, p0, y[ni]));
        }
      }
      VM_FENCE();  // prefetch DMA drained before publishing buffers
      __syncthreads();
    }

    // epilogue: y^T[d][q], d = ni*16+quad*4+r, q = l16; sum_acc holds full row-sum
    float inv = 1.f / sum_acc[0];
    size_t rb = ((size_t)bloc * SEQ + m + l16) * CH + hh * HD + quad * 4;
#pragma unroll
    for (int ni = 0; ni < 4; ni++) {
      bf16x4 o = {(bf16_t)(y[ni][0] * inv), (bf16_t)(y[ni][1] * inv),
                  (bf16_t)(y[ni][2] * inv), (bf16_t)(y[ni][3] * inv)};
      *(bf16x4*)&att[rb + ni * 16] = o;
    }
  }
}

// ---------------- output projection GEMM: 64x128 tiles, 4 CTAs/CU ----------------
__global__ __launch_bounds__(256) void proj_kernel(const bf16_t* __restrict__ A,
                                                   const bf16_t* __restrict__ Wp,
                                                   const float* __restrict__ bp,
                                                   float* __restrict__ out) {
  __shared__ __align__(16) bf16_t As[64 * BKK];    // 8 KB
  __shared__ __align__(16) bf16_t Bs[128 * BKK];   // 16 KB
  f32x4 acc[2][4];
#pragma unroll
  for (int i = 0; i < 2; i++)
#pragma unroll
    for (int j = 0; j < 4; j++) acc[i][j] = (f32x4){0.f, 0.f, 0.f, 0.f};

  // T1 XCD swizzle: 1024 blocks, 128 per XCD; n fastest -> full W cycles in L2.
  const int id = blockIdx.x;
  const int sid = ((id & 7) * 128) + (id >> 3);
  const int n0 = (sid % 8) * 128;
  const int m0 = (sid / 8) * 64;

  const int tid = threadIdx.x, lane = tid & 63, w = tid >> 6;
  const int quad = lane >> 4, l16 = lane & 15;
  const int wm = (w >> 1) << 5;                   // 2 wave-rows of 32
  const int wn = (w & 1) << 6;                    // 2 wave-cols of 64
  const int srow = tid >> 3;                      // 0..31
  const int scol = ((tid & 7) ^ (srow & 7)) << 3; // pre-swizzled source col
  const int dcol = (tid & 7) << 3;
  const int key = l16 & 7;

  const bf16_t* ga[2];
  bf16_t* la[2];
  const bf16_t* gb[4];
  bf16_t* lb[4];
#pragma unroll
  for (int p = 0; p < 2; p++) {
    int row = p * 32 + srow;
    ga[p] = A + (size_t)(m0 + row) * CH + scol;
    la[p] = As + row * BKK + dcol;
  }
#pragma unroll
  for (int p = 0; p < 4; p++) {
    int row = p * 32 + srow;
    gb[p] = Wp + (size_t)(n0 + row) * CH + scol;
    lb[p] = Bs + row * BKK + dcol;
  }
  for (int k0 = 0; k0 < CH; k0 += BKK) {
#pragma unroll
    for (int p = 0; p < 2; p++) g2lds16(ga[p] + k0, la[p]);
#pragma unroll
    for (int p = 0; p < 4; p++) g2lds16(gb[p] + k0, lb[p]);
    VM_FENCE();
    __syncthreads();
#pragma unroll
    for (int ki = 0; ki < 2; ki++) {
      bf16x8 av[2], bv[4];
#pragma unroll
      for (int i = 0; i < 2; i++)
        av[i] = *(const bf16x8*)&As[(wm + i * 16 + l16) * BKK +
                                    ((((ki << 2) | quad) ^ key) << 3)];
#pragma unroll
      for (int i = 0; i < 4; i++)
        bv[i] = *(const bf16x8*)&Bs[(wn + i * 16 + l16) * BKK +
                                    ((((ki << 2) | quad) ^ key) << 3)];
#pragma unroll
      for (int mi = 0; mi < 2; mi++)
#pragma unroll
        for (int ni = 0; ni < 4; ni++)
          acc[mi][ni] = mfma16(av[mi], bv[ni], acc[mi][ni]);
    }
    __syncthreads();
  }

  const int nbase = n0 + wn, mbase = m0 + wm;
#pragma unroll
  for (int mi = 0; mi < 2; mi++)
#pragma unroll
    for (int r = 0; r < 4; r++) {
      int m = mbase + mi * 16 + quad * 4 + r;
#pragma unroll
      for (int ni = 0; ni < 4; ni++) {
        int n = nbase + ni * 16 + l16;
        out[(size_t)m * CH + n] = acc[mi][ni][r] + bp[n];
      }
    }
}

extern "C" void kernel_launch(void* const* d_in, const int* in_sizes, int n_in,
                              void* d_out, int out_size, void* d_ws, size_t ws_size,
                              hipStream_t stream) {
  const float* x      = (const float*)d_in[0];
  const float* w_attn = (const float*)d_in[1];
  const float* b_attn = (const float*)d_in[2];
  const float* w_proj = (const float*)d_in[3];
  const float* b_proj = (const float*)d_in[4];
  const float* cosT   = (const float*)d_in[5];
  const float* sinT   = (const float*)d_in[6];
  float* out = (float*)d_out;

  bf16_t* xbf  = (bf16_t*)d_ws;
  bf16_t* wabf = xbf + (size_t)8192 * 1024;
  bf16_t* wpbf = wabf + (size_t)3072 * 1024;
  bf16_t* Qb   = wpbf + (size_t)1024 * 1024;
  bf16_t* Kb   = Qb + (size_t)8388608;
  bf16_t* VTb  = Kb + (size_t)8388608;
  bf16_t* attb = VTb + (size_t)8388608;

  cvt3_kernel<<<12288, 256, 0, stream>>>((const float4*)x, (ushort4*)xbf,
                                         (const float4*)w_attn, (ushort4*)wabf,
                                         (const float4*)w_proj, (ushort4*)wpbf);
  qkv_rope_kernel<<<dim3(1536), 256, 0, stream>>>(xbf, wabf, b_attn, cosT, sinT,
                                                  Qb, Kb, VTb);
  flash_kernel<<<dim3(512), 512, 0, stream>>>(Qb, Kb, VTb, attb);
  proj_kernel<<<dim3(1024), 256, 0, stream>>>(attb, wpbf, b_proj, out);
}